// Round 12
// baseline (265.451 us; speedup 1.0000x reference)
//
#include <hip/hip_runtime.h>
#include <hip/hip_bf16.h>
#include <stdint.h>

#define B_ROWS 16384
#define D_IN   512
#define H_DIM  1024
#define K_TOT  1536
#define NKT    48          // K-tiles of 32

typedef __attribute__((ext_vector_type(8)))  short bf16x8;
typedef __attribute__((ext_vector_type(4)))  float f32x4;
typedef __attribute__((ext_vector_type(4)))  float float4v;
typedef __attribute__((ext_vector_type(8)))  unsigned short u16x8;

__device__ __forceinline__ unsigned short f2bf(float f) {
    uint32_t u = __float_as_uint(f);
    u = (u + 0x7FFFu + ((u >> 16) & 1u)) >> 16;   // RNE
    return (unsigned short)u;
}

// ---------------------------------------------------------------------------
// Ag fragment-linear, 256-row tiles, BK=32:
//   granule g = ((bm*48 + T)*16 + chunk)*64 + lane    (16 B)
//   lane l: row = bm*256 + chunk*16 + (l&15) ; k = T*32 + (l>>4)*8 + j
// ---------------------------------------------------------------------------
__global__ void cvt_A(const float* __restrict__ x, const float* __restrict__ h,
                      unsigned short* __restrict__ Ag) {
    int t     = blockIdx.x * blockDim.x + threadIdx.x;
    int lane  = t & 63;
    int chunk = (t >> 6) & 15;
    int rest  = t >> 10;            // bm*48 + T
    int T     = rest % 48;
    int bm    = rest / 48;
    int row   = bm * 256 + chunk * 16 + (lane & 15);
    int k     = T * 32 + (lane >> 4) * 8;
    const float* src = (k < 512) ? (x + (size_t)row * D_IN + k)
                                 : (h + (size_t)row * H_DIM + (k - 512));
    float4v v0 = *(const float4v*)(src);
    float4v v1 = *(const float4v*)(src + 4);
    u16x8 o;
    o[0] = f2bf(v0[0]); o[1] = f2bf(v0[1]); o[2] = f2bf(v0[2]); o[3] = f2bf(v0[3]);
    o[4] = f2bf(v1[0]); o[5] = f2bf(v1[1]); o[6] = f2bf(v1[2]); o[7] = f2bf(v1[3]);
    *(u16x8*)(Ag + (size_t)t * 8) = o;
}

// ---------------------------------------------------------------------------
// Bg fragment-linear, gate-interleaved cols (granularity 16, R1-proven):
//   col c = (h>>4)*64 + gate*16 + (h&15)
//   granule g = ((bn*48 + T)*16 + chunk)*64 + lane
//   lane l: c = bn*256 + chunk*16 + (l&15) ; k = T*32 + (l>>4)*8 + j
// ---------------------------------------------------------------------------
__global__ void cvt_B(const float* __restrict__ Ui, const float* __restrict__ Uf,
                      const float* __restrict__ Uo, const float* __restrict__ Uc,
                      const float* __restrict__ Wi, const float* __restrict__ Wf,
                      const float* __restrict__ Wo, const float* __restrict__ Wc,
                      unsigned short* __restrict__ Bg) {
    int t     = blockIdx.x * blockDim.x + threadIdx.x;
    int lane  = t & 63;
    int chunk = (t >> 6) & 15;
    int rest  = t >> 10;            // bn*48 + T
    int T     = rest % 48;
    int bn    = rest / 48;
    int c     = bn * 256 + chunk * 16 + (lane & 15);
    int g     = (c >> 4) & 3;
    int hcol  = ((c >> 6) << 4) | (c & 15);
    int k     = T * 32 + (lane >> 4) * 8;
    const float* up = (g == 0) ? Ui : (g == 1) ? Uf : (g == 2) ? Uo : Uc;
    const float* wp = (g == 0) ? Wi : (g == 1) ? Wf : (g == 2) ? Wo : Wc;
    u16x8 o;
    if (k < 512) {
        const float* s = up + (size_t)k * H_DIM + hcol;
        #pragma unroll
        for (int i = 0; i < 8; ++i) o[i] = f2bf(s[(size_t)i * H_DIM]);
    } else {
        const float* s = wp + (size_t)(k - 512) * H_DIM + hcol;
        #pragma unroll
        for (int i = 0; i < 8; ++i) o[i] = f2bf(s[(size_t)i * H_DIM]);
    }
    *(u16x8*)(Bg + (size_t)t * 8) = o;
}

__global__ void cvt_bias(const float* __restrict__ Uib, const float* __restrict__ Ufb,
                         const float* __restrict__ Uob, const float* __restrict__ Ucb,
                         const float* __restrict__ Wib, const float* __restrict__ Wfb,
                         const float* __restrict__ Wob, const float* __restrict__ Wcb,
                         float* __restrict__ bias) {
    int t = blockIdx.x * blockDim.x + threadIdx.x;
    int g = t >> 10, h = t & 1023;
    const float* ub = (g == 0) ? Uib : (g == 1) ? Ufb : (g == 2) ? Uob : Ucb;
    const float* wb = (g == 0) ? Wib : (g == 1) ? Wfb : (g == 2) ? Wob : Wcb;
    bias[t] = ub[h] + wb[h];
}

// ---------------------------------------------------------------------------
// 256x256 GEMM, 16x16x32 MFMA, BK=32, RING-5 (160 KB), RELAXED FENCES.
// 8 waves 2Mx4N, per-wave 128x64, acc[8][4].
// Slot (32 KB) = A region (16 KB, chunks 0..15) + B region (+16384).
// Phase pair per tile t (slot t%5):
//   P_a: read A.h0 (4 b128) + B (4 b128 -> bPers); stage A(t+3); barrier;
//        setprio(1); 16 MFMA (acc[0..3]); setprio(0); barrier.
//   P_b: read A.h1 (4); stage B(t+3); barrier; setprio; 16 MFMA (acc[4..7]);
//        setprio; s_waitcnt vmcnt(2); barrier.
// NO memory clobbers / sched_barriers: compiler may hoist ds_reads <=1 phase
// back (pinned by may-aliasing with the previous phase's glds) -> LDS reads
// overlap the MFMA cluster. Hoist-safety: A(t) retired by P_b(t-3)'s gate,
// B(t) by P_b(t-2)'s gate -- both >=2 phases before first read. WAR: slot
// re-staged >=4 barriers after its last read. Gates never 0 (vmcnt(2)).
// ---------------------------------------------------------------------------
__global__ __launch_bounds__(512) void lstm_gemm(
        const unsigned short* __restrict__ Ag, const unsigned short* __restrict__ Bg,
        const float* __restrict__ bias, const float* __restrict__ c_old,
        float* __restrict__ out) {
    __shared__ __align__(1024) char lds[163840];   // 5 slots x 32 KiB

    const int tid = threadIdx.x;
    const int l   = tid & 63;
    const int wv  = tid >> 6;
    const int wm  = wv >> 2;      // 0..1  (128-row slice)
    const int wn  = wv & 3;       // 0..3  (64-col slice)

    // XCD swizzle: per XCD 8bm x 4bn
    const int orig = blockIdx.x;              // 1024 blocks
    const int xcd  = orig & 7;
    const int jj   = orig >> 3;
    const int bn   = (xcd & 3) * 4 + (jj & 3);     // 0..15
    const int bm   = (xcd >> 2) * 32 + (jj >> 2);  // 0..63

    // staging sources: tile block = 16 chunks * 512 ushorts = 8192 ushorts
    const unsigned short* aSrc = Ag + (size_t)bm * 48 * 8192 + (size_t)(2 * wv) * 512 + l * 8;
    const unsigned short* bSrc = Bg + (size_t)bn * 48 * 8192 + (size_t)(2 * wv) * 512 + l * 8;

    // LDS read lane offsets
    const int aRd = wm * 8192 + l * 16;            // + (q*4+m)*1024
    const int bRd = 16384 + wn * 4096 + l * 16;    // + n*1024

#define GLDS(SRC, DST) __builtin_amdgcn_global_load_lds(                            \
        (const __attribute__((address_space(1))) void*)(SRC),                       \
        (__attribute__((address_space(3))) void*)(DST), 16, 0, 0)

#define STAGE_A(T, SLOTBASE) do {                                                   \
    const unsigned short* _s = aSrc + (size_t)(T) * 8192;                           \
    char* _d = (char*)lds + (SLOTBASE) + wv * 2048;                                 \
    GLDS(_s, _d);  GLDS(_s + 512, _d + 1024);                                       \
} while (0)

#define STAGE_B(T, SLOTBASE) do {                                                   \
    const unsigned short* _s = bSrc + (size_t)(T) * 8192;                           \
    char* _d = (char*)lds + (SLOTBASE) + 16384 + wv * 2048;                         \
    GLDS(_s, _d);  GLDS(_s + 512, _d + 1024);                                       \
} while (0)

    f32x4 acc[8][4] = {};
    bf16x8 bPers[4];

    // ---- prologue: stage tiles 0,1,2 -> slots 0,1,2 (A,B each) ----
    STAGE_A(0, 0);      STAGE_B(0, 0);
    STAGE_A(1, 32768);  STAGE_B(1, 32768);
    STAGE_A(2, 65536);  STAGE_B(2, 65536);
    asm volatile("s_waitcnt vmcnt(2)");
    __builtin_amdgcn_s_barrier();

    int rdBase = 0;        // (t%5)*32768
    int ssBase = 98304;    // ((t+3)%5)*32768

    // ---- main loop: 48 tiles x 2 phases ----
    #pragma unroll 1
    for (int t = 0; t < NKT; ++t) {
        int ts = t + 3; if (ts >= NKT) ts -= NKT;   // wrapped: staged, never read

        // P_a
        {
            const char* _A = (const char*)lds + rdBase + aRd;
            const char* _B = (const char*)lds + rdBase + bRd;
            bf16x8 aF[4];
            #pragma unroll
            for (int m = 0; m < 4; ++m)
                aF[m] = *(const bf16x8*)(_A + m * 1024);
            #pragma unroll
            for (int n = 0; n < 4; ++n)
                bPers[n] = *(const bf16x8*)(_B + n * 1024);
            STAGE_A(ts, ssBase);
            __builtin_amdgcn_s_barrier();
            __builtin_amdgcn_s_setprio(1);
            #pragma unroll
            for (int m = 0; m < 4; ++m)
                #pragma unroll
                for (int n = 0; n < 4; ++n)
                    acc[m][n] = __builtin_amdgcn_mfma_f32_16x16x32_bf16(
                        aF[m], bPers[n], acc[m][n], 0, 0, 0);
            __builtin_amdgcn_s_setprio(0);
            __builtin_amdgcn_s_barrier();
        }
        // P_b
        {
            const char* _A = (const char*)lds + rdBase + aRd + 4096;
            bf16x8 aF[4];
            #pragma unroll
            for (int m = 0; m < 4; ++m)
                aF[m] = *(const bf16x8*)(_A + m * 1024);
            STAGE_B(ts, ssBase);
            __builtin_amdgcn_s_barrier();
            __builtin_amdgcn_s_setprio(1);
            #pragma unroll
            for (int m = 0; m < 4; ++m)
                #pragma unroll
                for (int n = 0; n < 4; ++n)
                    acc[4 + m][n] = __builtin_amdgcn_mfma_f32_16x16x32_bf16(
                        aF[m], bPers[n], acc[4 + m][n], 0, 0, 0);
            __builtin_amdgcn_s_setprio(0);
            asm volatile("s_waitcnt vmcnt(2)");
            __builtin_amdgcn_s_barrier();
        }

        rdBase = (rdBase == 131072) ? 0 : rdBase + 32768;
        ssBase = (ssBase == 131072) ? 0 : ssBase + 32768;
    }
    asm volatile("s_waitcnt vmcnt(0)");   // drain wrapped stagings

    // ---- fused LSTM epilogue: gate = n (in-lane), hh = (bn*4+wn)*16 + col ----
    const int hh  = (bn * 4 + wn) * 16 + (l & 15);
    const float bi  = bias[hh];
    const float bff = bias[1024 + hh];
    const float bo  = bias[2048 + hh];
    const float bc  = bias[3072 + hh];

    #pragma unroll
    for (int a = 0; a < 8; ++a) {
        const int rb = bm * 256 + wm * 128 + (a >> 2) * 64 + (a & 3) * 16 + ((l >> 4) * 4);
        #pragma unroll
        for (int j = 0; j < 4; ++j) {
            const int r = rb + j;
            float iv = acc[a][0][j] + bi;
            float fv = acc[a][1][j] + bff;
            float ov = acc[a][2][j] + bo;
            float gv = acc[a][3][j] + bc;
            float it = 1.f / (1.f + __expf(-iv));
            float ft = 1.f / (1.f + __expf(-fv));
            float ot = 1.f / (1.f + __expf(-ov));
            float gt = 1.f - 2.f / (1.f + __expf(2.f * gv));
            float co = c_old[(size_t)r * H_DIM + hh];
            float cn = it * gt + ft * co;
            float th = 1.f - 2.f / (1.f + __expf(2.f * cn));
            out[(size_t)r * H_DIM + hh] = ot * th;                          // h_new
            out[(size_t)B_ROWS * H_DIM + (size_t)r * H_DIM + hh] = cn;      // c
        }
    }
#undef STAGE_A
#undef STAGE_B
#undef GLDS
}

extern "C" void kernel_launch(void* const* d_in, const int* in_sizes, int n_in,
                              void* d_out, int out_size, void* d_ws, size_t ws_size,
                              hipStream_t stream) {
    const float* x  = (const float*)d_in[0];
    const float* h0 = (const float*)d_in[1];
    const float* c0 = (const float*)d_in[2];
    const float* Uw[4] = {(const float*)d_in[3],  (const float*)d_in[5],
                          (const float*)d_in[7],  (const float*)d_in[9]};
    const float* Ub[4] = {(const float*)d_in[4],  (const float*)d_in[6],
                          (const float*)d_in[8],  (const float*)d_in[10]};
    const float* Ww[4] = {(const float*)d_in[11], (const float*)d_in[13],
                          (const float*)d_in[15], (const float*)d_in[17]};
    const float* Wb[4] = {(const float*)d_in[12], (const float*)d_in[14],
                          (const float*)d_in[16], (const float*)d_in[18]};

    unsigned short* Ag = (unsigned short*)d_ws;                 // 48 MiB
    unsigned short* Bg = Ag + (size_t)B_ROWS * K_TOT;           // 12 MiB
    float* bias        = (float*)(Bg + (size_t)4096 * K_TOT);   // 16 KiB
    float* out         = (float*)d_out;

    cvt_A<<<12288, 256, 0, stream>>>(x, h0, Ag);
    cvt_B<<<3072, 256, 0, stream>>>(Uw[0], Uw[1], Uw[2], Uw[3],
                                    Ww[0], Ww[1], Ww[2], Ww[3], Bg);
    cvt_bias<<<16, 256, 0, stream>>>(Ub[0], Ub[1], Ub[2], Ub[3],
                                     Wb[0], Wb[1], Wb[2], Wb[3], bias);
    lstm_gemm<<<1024, 512, 0, stream>>>(Ag, Bg, bias, c0, out);
}

// Round 13
// 257.708 us; speedup vs baseline: 1.0300x; 1.0300x over previous
//
#include <hip/hip_runtime.h>
#include <hip/hip_bf16.h>
#include <stdint.h>

#define B_ROWS 16384
#define D_IN   512
#define H_DIM  1024
#define K_TOT  1536
#define NKT    48          // K-tiles of 32

typedef __attribute__((ext_vector_type(8)))  short bf16x8;
typedef __attribute__((ext_vector_type(4)))  float f32x4;
typedef __attribute__((ext_vector_type(4)))  float float4v;
typedef __attribute__((ext_vector_type(8)))  unsigned short u16x8;

__device__ __forceinline__ unsigned short f2bf(float f) {
    uint32_t u = __float_as_uint(f);
    u = (u + 0x7FFFu + ((u >> 16) & 1u)) >> 16;   // RNE
    return (unsigned short)u;
}

// ---------------------------------------------------------------------------
// Ag fragment-linear, 256-row tiles, BK=32:
//   granule g = ((bm*48 + T)*16 + chunk)*64 + lane    (16 B)
//   lane l: row = bm*256 + chunk*16 + (l&15) ; k = T*32 + (l>>4)*8 + j
// ---------------------------------------------------------------------------
__global__ void cvt_A(const float* __restrict__ x, const float* __restrict__ h,
                      unsigned short* __restrict__ Ag) {
    int t     = blockIdx.x * blockDim.x + threadIdx.x;
    int lane  = t & 63;
    int chunk = (t >> 6) & 15;
    int rest  = t >> 10;            // bm*48 + T
    int T     = rest % 48;
    int bm    = rest / 48;
    int row   = bm * 256 + chunk * 16 + (lane & 15);
    int k     = T * 32 + (lane >> 4) * 8;
    const float* src = (k < 512) ? (x + (size_t)row * D_IN + k)
                                 : (h + (size_t)row * H_DIM + (k - 512));
    float4v v0 = *(const float4v*)(src);
    float4v v1 = *(const float4v*)(src + 4);
    u16x8 o;
    o[0] = f2bf(v0[0]); o[1] = f2bf(v0[1]); o[2] = f2bf(v0[2]); o[3] = f2bf(v0[3]);
    o[4] = f2bf(v1[0]); o[5] = f2bf(v1[1]); o[6] = f2bf(v1[2]); o[7] = f2bf(v1[3]);
    *(u16x8*)(Ag + (size_t)t * 8) = o;
}

// ---------------------------------------------------------------------------
// Bg fragment-linear, gate-interleaved cols (granularity 16, R1-proven):
//   col c = (h>>4)*64 + gate*16 + (h&15)
//   granule g = ((bn*48 + T)*16 + chunk)*64 + lane
//   lane l: c = bn*256 + chunk*16 + (l&15) ; k = T*32 + (l>>4)*8 + j
// ---------------------------------------------------------------------------
__global__ void cvt_B(const float* __restrict__ Ui, const float* __restrict__ Uf,
                      const float* __restrict__ Uo, const float* __restrict__ Uc,
                      const float* __restrict__ Wi, const float* __restrict__ Wf,
                      const float* __restrict__ Wo, const float* __restrict__ Wc,
                      unsigned short* __restrict__ Bg) {
    int t     = blockIdx.x * blockDim.x + threadIdx.x;
    int lane  = t & 63;
    int chunk = (t >> 6) & 15;
    int rest  = t >> 10;            // bn*48 + T
    int T     = rest % 48;
    int bn    = rest / 48;
    int c     = bn * 256 + chunk * 16 + (lane & 15);
    int g     = (c >> 4) & 3;
    int hcol  = ((c >> 6) << 4) | (c & 15);
    int k     = T * 32 + (lane >> 4) * 8;
    const float* up = (g == 0) ? Ui : (g == 1) ? Uf : (g == 2) ? Uo : Uc;
    const float* wp = (g == 0) ? Wi : (g == 1) ? Wf : (g == 2) ? Wo : Wc;
    u16x8 o;
    if (k < 512) {
        const float* s = up + (size_t)k * H_DIM + hcol;
        #pragma unroll
        for (int i = 0; i < 8; ++i) o[i] = f2bf(s[(size_t)i * H_DIM]);
    } else {
        const float* s = wp + (size_t)(k - 512) * H_DIM + hcol;
        #pragma unroll
        for (int i = 0; i < 8; ++i) o[i] = f2bf(s[(size_t)i * H_DIM]);
    }
    *(u16x8*)(Bg + (size_t)t * 8) = o;
}

__global__ void cvt_bias(const float* __restrict__ Uib, const float* __restrict__ Ufb,
                         const float* __restrict__ Uob, const float* __restrict__ Ucb,
                         const float* __restrict__ Wib, const float* __restrict__ Wfb,
                         const float* __restrict__ Wob, const float* __restrict__ Wcb,
                         float* __restrict__ bias) {
    int t = blockIdx.x * blockDim.x + threadIdx.x;
    int g = t >> 10, h = t & 1023;
    const float* ub = (g == 0) ? Uib : (g == 1) ? Ufb : (g == 2) ? Uob : Ucb;
    const float* wb = (g == 0) ? Wib : (g == 1) ? Wfb : (g == 2) ? Wob : Wcb;
    bias[t] = ub[h] + wb[h];
}

// ---------------------------------------------------------------------------
// 256x256 GEMM, 16x16x32 MFMA, BK=32, RING-5 (160 KB), MINIMUM SYNC:
// exactly ONE barrier + ONE counted vmcnt(4) per K-tile. Per tile t:
//   { 12 ds_read (8 A + 4 B, fragment-linear, conflict-free) ;
//     4 glds stage tile t+3 -> slot (t+3)%5 ;
//     32 MFMA (acc[8][4], full K=32) ;
//     s_waitcnt vmcnt(4) ; s_barrier }
// No lgkm asm / sched_barriers / memory clobbers: compiler interleaves
// ds_reads under MFMAs and may hoist tile t+1's reads into tile t (safe:
// t+1's stage landed by end of t-1; gate at end of t leaves only t+3's 4
// glds outstanding). WAR: stage(t+3) targets slot (t-2)%5, last read in
// tile t-2, separated by barriers at end of t-2 and t-1. Gates never 0.
// ---------------------------------------------------------------------------
__global__ __launch_bounds__(512) void lstm_gemm(
        const unsigned short* __restrict__ Ag, const unsigned short* __restrict__ Bg,
        const float* __restrict__ bias, const float* __restrict__ c_old,
        float* __restrict__ out) {
    __shared__ __align__(1024) char lds[163840];   // 5 slots x 32 KiB

    const int tid = threadIdx.x;
    const int l   = tid & 63;
    const int wv  = tid >> 6;
    const int wm  = wv >> 2;      // 0..1  (128-row slice)
    const int wn  = wv & 3;       // 0..3  (64-col slice)

    // XCD swizzle: per XCD 8bm x 4bn
    const int orig = blockIdx.x;              // 1024 blocks
    const int xcd  = orig & 7;
    const int jj   = orig >> 3;
    const int bn   = (xcd & 3) * 4 + (jj & 3);     // 0..15
    const int bm   = (xcd >> 2) * 32 + (jj >> 2);  // 0..63

    // staging sources: tile block = 16 chunks * 512 ushorts = 8192 ushorts
    const unsigned short* aSrc = Ag + (size_t)bm * 48 * 8192 + (size_t)(2 * wv) * 512 + l * 8;
    const unsigned short* bSrc = Bg + (size_t)bn * 48 * 8192 + (size_t)(2 * wv) * 512 + l * 8;

    // LDS read lane offsets
    const int aRd = wm * 8192 + l * 16;            // + i*1024, i=0..7
    const int bRd = 16384 + wn * 4096 + l * 16;    // + n*1024, n=0..3

#define GLDS(SRC, DST) __builtin_amdgcn_global_load_lds(                            \
        (const __attribute__((address_space(1))) void*)(SRC),                       \
        (__attribute__((address_space(3))) void*)(DST), 16, 0, 0)

#define STAGE_T(T, SLOTBASE) do {                                                   \
    const unsigned short* _sa = aSrc + (size_t)(T) * 8192;                          \
    const unsigned short* _sb = bSrc + (size_t)(T) * 8192;                          \
    char* _d = (char*)lds + (SLOTBASE) + wv * 2048;                                 \
    GLDS(_sa, _d);          GLDS(_sa + 512, _d + 1024);                             \
    GLDS(_sb, _d + 16384);  GLDS(_sb + 512, _d + 16384 + 1024);                     \
} while (0)

    f32x4 acc[8][4] = {};

    // ---- prologue: stage tiles 0,1,2 -> slots 0,1,2 ----
    STAGE_T(0, 0);
    STAGE_T(1, 32768);
    STAGE_T(2, 65536);
    asm volatile("s_waitcnt vmcnt(4)");   // tiles 0,1 resident
    __builtin_amdgcn_s_barrier();

    int rdBase = 0;        // (t%5)*32768
    int ssBase = 98304;    // ((t+3)%5)*32768

    // ---- main loop: 48 tiles, one barrier + one vmcnt(4) each ----
    #pragma unroll 1
    for (int t = 0; t < NKT; ++t) {
        int ts = t + 3; if (ts >= NKT) ts -= NKT;   // wrapped: staged, never read

        const char* _A = (const char*)lds + rdBase + aRd;
        const char* _B = (const char*)lds + rdBase + bRd;
        bf16x8 aF[8], bF[4];
        #pragma unroll
        for (int i = 0; i < 8; ++i)
            aF[i] = *(const bf16x8*)(_A + i * 1024);
        #pragma unroll
        for (int n = 0; n < 4; ++n)
            bF[n] = *(const bf16x8*)(_B + n * 1024);

        STAGE_T(ts, ssBase);

        __builtin_amdgcn_s_setprio(1);
        #pragma unroll
        for (int i = 0; i < 8; ++i)
            #pragma unroll
            for (int n = 0; n < 4; ++n)
                acc[i][n] = __builtin_amdgcn_mfma_f32_16x16x32_bf16(
                    aF[i], bF[n], acc[i][n], 0, 0, 0);
        __builtin_amdgcn_s_setprio(0);

        asm volatile("s_waitcnt vmcnt(4)");
        __builtin_amdgcn_s_barrier();

        rdBase = (rdBase == 131072) ? 0 : rdBase + 32768;
        ssBase = (ssBase == 131072) ? 0 : ssBase + 32768;
    }
    asm volatile("s_waitcnt vmcnt(0)");   // drain wrapped stagings

    // ---- fused LSTM epilogue: gate = n (in-lane), hh = (bn*4+wn)*16 + col ----
    const int hh  = (bn * 4 + wn) * 16 + (l & 15);
    const float bi  = bias[hh];
    const float bff = bias[1024 + hh];
    const float bo  = bias[2048 + hh];
    const float bc  = bias[3072 + hh];

    #pragma unroll
    for (int a = 0; a < 8; ++a) {
        const int rb = bm * 256 + wm * 128 + (a >> 2) * 64 + (a & 3) * 16 + ((l >> 4) * 4);
        #pragma unroll
        for (int j = 0; j < 4; ++j) {
            const int r = rb + j;
            float iv = acc[a][0][j] + bi;
            float fv = acc[a][1][j] + bff;
            float ov = acc[a][2][j] + bo;
            float gv = acc[a][3][j] + bc;
            float it = 1.f / (1.f + __expf(-iv));
            float ft = 1.f / (1.f + __expf(-fv));
            float ot = 1.f / (1.f + __expf(-ov));
            float gt = 1.f - 2.f / (1.f + __expf(2.f * gv));
            float co = c_old[(size_t)r * H_DIM + hh];
            float cn = it * gt + ft * co;
            float th = 1.f - 2.f / (1.f + __expf(2.f * cn));
            out[(size_t)r * H_DIM + hh] = ot * th;                          // h_new
            out[(size_t)B_ROWS * H_DIM + (size_t)r * H_DIM + hh] = cn;      // c
        }
    }
#undef STAGE_T
#undef GLDS
}

extern "C" void kernel_launch(void* const* d_in, const int* in_sizes, int n_in,
                              void* d_out, int out_size, void* d_ws, size_t ws_size,
                              hipStream_t stream) {
    const float* x  = (const float*)d_in[0];
    const float* h0 = (const float*)d_in[1];
    const float* c0 = (const float*)d_in[2];
    const float* Uw[4] = {(const float*)d_in[3],  (const float*)d_in[5],
                          (const float*)d_in[7],  (const float*)d_in[9]};
    const float* Ub[4] = {(const float*)d_in[4],  (const float*)d_in[6],
                          (const float*)d_in[8],  (const float*)d_in[10]};
    const float* Ww[4] = {(const float*)d_in[11], (const float*)d_in[13],
                          (const float*)d_in[15], (const float*)d_in[17]};
    const float* Wb[4] = {(const float*)d_in[12], (const float*)d_in[14],
                          (const float*)d_in[16], (const float*)d_in[18]};

    unsigned short* Ag = (unsigned short*)d_ws;                 // 48 MiB
    unsigned short* Bg = Ag + (size_t)B_ROWS * K_TOT;           // 12 MiB
    float* bias        = (float*)(Bg + (size_t)4096 * K_TOT);   // 16 KiB
    float* out         = (float*)d_out;

    cvt_A<<<12288, 256, 0, stream>>>(x, h0, Ag);
    cvt_B<<<3072, 256, 0, stream>>>(Uw[0], Uw[1], Uw[2], Uw[3],
                                    Ww[0], Ww[1], Ww[2], Ww[3], Bg);
    cvt_bias<<<16, 256, 0, stream>>>(Ub[0], Ub[1], Ub[2], Ub[3],
                                     Wb[0], Wb[1], Wb[2], Wb[3], bias);
    lstm_gemm<<<1024, 512, 0, stream>>>(Ag, Bg, bias, c0, out);
}